// Round 16
// baseline (97498.828 us; speedup 1.0000x reference)
//
#include <hip/hip_runtime.h>
#include <cstdint>
#include <cstddef>

#define NWG 64
#define NTHR 512
#define UPW 16  // hidden units per WG
#define TSTEPS 16384
#define HDIM 1024
#define EDIM 13
#define HLDIM 512

typedef unsigned long long ull;

// ---------------------------------------------------------------------------
// Init kernel: re-arm the tagged h-record ring and u-record every call (d_ws
// is poisoned once with 0xAA and never re-poisoned between graph replays; a
// finished replay also leaves end-state tags behind, so every tag word must
// be rewritten each launch).
// hrec[parity][i] = { low32: f32 h value, high32: u32 step tag }, 4 parities.
// ---------------------------------------------------------------------------
__global__ void k_init(const float* __restrict__ h0, ull* __restrict__ hrec,
                       ull* __restrict__ urec) {
  int i = threadIdx.x;
  hrec[i] = (ull)__float_as_uint(h0[i]);  // {h0, tag=0}
  hrec[HDIM + i] = 0ull;
  hrec[2 * HDIM + i] = 0ull;
  hrec[3 * HDIM + i] = 0ull;
  if (i < HLDIM) urec[i] = 0ull;
}

// ---------------------------------------------------------------------------
// Persistent LSTM kernel. R13 protocol (best: 48.7 ms) with the W-stream
// moved OFF the post-barrier critical path:
//  - units 0..7: W in 128 KB LDS (post-barrier LDS reads ~0.2us).
//  - units 8..15: W prefetched into 16 float4 regs at the TOP of each step,
//    BEFORE the poll. Addresses salted with never*t (never==0 at runtime) so
//    LICM cannot hoist them into a loop-carried pinned array (the allocator
//    spills those - proven 7x in R3-R15). Loads cannot sink across
//    __syncthreads; vmcnt retires in order, so the poll's waits drain them.
//  - post-barrier: one h-read feeds both halves (accL += wLDS*hv,
//    accS += wreg*hv) -> pure VALU+LDS, no global/scratch traffic.
// 64 WGs (128-WG rendezvous costs +1.5-2us/step: R6/R15). Wave v owns units
// v (LDS W) and 8+v (streamed W); each 16-lane group handles gate g of both;
// lane 0 integrates both cells and publishes 2 records.
// Cross-WG sync unchanged (proven): self-validating {value, tag} 8-byte
// records, 4-deep parity ring, relaxed agent-scope 64-bit atomics
// (single-copy, serviced at the device coherent point -> immune to
// non-coherent per-XCD L2s). One coherent round trip + one barrier per step.
// ---------------------------------------------------------------------------
__global__ __launch_bounds__(NTHR) void k_main(
    const float* __restrict__ x, const float* __restrict__ c0,
    const float* __restrict__ Wih, const float* __restrict__ Whh,
    const float* __restrict__ bih, const float* __restrict__ bhh,
    const float* __restrict__ W1, const float* __restrict__ b1,
    const float* __restrict__ W2, const float* __restrict__ b2,
    float* __restrict__ out, ull* hrec, ull* urec, int never) {
  const int w = blockIdx.x;
  const int tid = threadIdx.x;
  const int wave = tid >> 6;  // 0..7: owns units (wave) and (8+wave)
  const int lane = tid & 63;
  const int g = (lane >> 4) & 3;  // gate group within the wave
  const int sub = lane & 15;      // 16 threads/row, 64 cols each
  const int row_l = 4 * wave + g;       // LDS-half row 0..31
  const int row_s = 32 + 4 * wave + g;  // streamed-half row in wih tables
  const int grow_s = g * HDIM + w * UPW + 8 + wave;  // streamed global row

  __shared__ float4 lds_w4[32 * 256];  // units 0..7, row r=4v+g, 128 KB
  __shared__ float4 lds_h4[2 * 256];   // [parity][col4]
  __shared__ float lds_wih[64][17];    // rows 0-31 LDS-half, 32-63 streamed
  __shared__ float lds_bsum[64];
  __shared__ float lds_xbuf[2][16];
  __shared__ float lds_r0[8], lds_r1[8];
  float* lds_hf = (float*)lds_h4;  // [2][1024] flat

  // ---- stage W for units 0..7 into LDS (one-time, coalesced) -------------
#pragma unroll
  for (int it = 0; it < 16; ++it) {
    int idx = it * NTHR + tid;  // 0..8191 float4s
    int r = idx >> 8;           // LDS row 0..31 (r = 4*v + g)
    int c4 = idx & 255;
    int v_ = r >> 2, g_ = r & 3;
    int grow = g_ * HDIM + UPW * w + v_;
    lds_w4[r * 256 + c4] = ((const float4*)(Whh + (size_t)grow * HDIM))[c4];
  }
  if (tid < 64) {
    // rows 0-31: units 0-7 (lu = tid>>2 in 0..7); rows 32-63: units 8-15
    int half = tid >> 5, rr = tid & 31;
    int lu_ = rr >> 2, g_ = rr & 3;
    int gr2 = g_ * HDIM + UPW * w + 8 * half + lu_;
#pragma unroll
    for (int e = 0; e < EDIM; ++e) lds_wih[tid][e] = Wih[gr2 * EDIM + e];
    lds_bsum[tid] = bih[gr2] + bhh[gr2];
  }
  // cell states: lane 0 of wave v owns units v and 8+v
  float cstL = c0[UPW * w + wave];
  float cstS = c0[UPW * w + 8 + wave];
  __syncthreads();

  const float gsc = (g == 2) ? 2.f : 1.f;  // tanh via 2*sigmoid(2x)-1
  const float4* wlrow = lds_w4 + (size_t)row_l * 256;
  const float4* wbase_s = (const float4*)(Whh + (size_t)grow_s * HDIM);

  for (int t = 1; t <= TSTEPS; ++t) {
    const int lp = (t - 1) & 1;  // LDS parity (2-deep, barrier-separated)

    // ---- W prefetch for the streamed unit, issued BEFORE the poll.
    // never==0 at runtime; never*t defeats LICM so the loads stay in-loop
    // (a hoisted loop-carried array would be spilled by the allocator).
    const float4* wrow_s = wbase_s + never * t;
    float4 wreg[16];
#pragma unroll
    for (int i = 0; i < 16; ++i)
      wreg[i] = wrow_s[sub * 16 + ((i + sub) & 15)];

    // ---- x_t prefetch (also pre-poll)
    float xv = 0.f;
    if (tid < EDIM) xv = x[(size_t)(t - 1) * EDIM + tid];

    // ---- poll this thread's two {h, tag} chunks of h_{t-1}; the poll load
    // IS the data load (one MALL round trip). 4-deep ring: overwrite of a
    // tag-t chunk (by tag t+4) needs three cross-WG dependence chains of
    // separation -> overwrite-before-read unreachable. The poll's waits
    // drain the W-prefetch (vmcnt retires in order).
    const ull* src = hrec + (size_t)((t - 1) & 3) * HDIM;
    const unsigned want = (unsigned)(t - 1);
    ull v0 = __hip_atomic_load(&src[tid], __ATOMIC_RELAXED,
                               __HIP_MEMORY_SCOPE_AGENT);
    ull v1 = __hip_atomic_load(&src[tid + NTHR], __ATOMIC_RELAXED,
                               __HIP_MEMORY_SCOPE_AGENT);
    for (;;) {
      bool b0 = (unsigned)(v0 >> 32) == want;
      bool b1 = (unsigned)(v1 >> 32) == want;
      if (b0 && b1) break;
      if (!b0)
        v0 = __hip_atomic_load(&src[tid], __ATOMIC_RELAXED,
                               __HIP_MEMORY_SCOPE_AGENT);
      if (!b1)
        v1 = __hip_atomic_load(&src[tid + NTHR], __ATOMIC_RELAXED,
                               __HIP_MEMORY_SCOPE_AGENT);
    }
    lds_hf[lp * HDIM + tid] = __uint_as_float((unsigned)v0);
    lds_hf[lp * HDIM + tid + NTHR] = __uint_as_float((unsigned)v1);
    if (tid < EDIM) lds_xbuf[lp][tid] = xv;
    __syncthreads();

    // ---- both gate rows: one h-read feeds the LDS-W and streamed-W chains
    float l0 = 0.f, l1 = 0.f, s0 = 0.f, s1 = 0.f;
    if (sub == 0) {
      l0 = lds_bsum[row_l];
      s0 = lds_bsum[row_s];
#pragma unroll
      for (int e = 0; e < EDIM; ++e) {
        l0 += lds_wih[row_l][e] * lds_xbuf[lp][e];
        s0 += lds_wih[row_s][e] * lds_xbuf[lp][e];
      }
    }
    const float4* hb = lds_h4 + lp * 256;
#pragma unroll
    for (int i = 0; i < 16; ++i) {
      int ii = sub * 16 + ((i + sub) & 15);
      float4 hv = hb[ii];
      float4 wv = wlrow[ii];
      float4 ws = wreg[i];
      float pl = wv.x * hv.x + wv.y * hv.y + wv.z * hv.z + wv.w * hv.w;
      float ps = ws.x * hv.x + ws.y * hv.y + ws.z * hv.z + ws.w * hv.w;
      if (i & 1) {
        l1 += pl;
        s1 += ps;
      } else {
        l0 += pl;
        s0 += ps;
      }
    }
    float accL = l0 + l1, accS = s0 + s1;
    accL += __shfl_xor(accL, 1);
    accS += __shfl_xor(accS, 1);
    accL += __shfl_xor(accL, 2);
    accS += __shfl_xor(accS, 2);
    accL += __shfl_xor(accL, 4);
    accS += __shfl_xor(accS, 4);
    accL += __shfl_xor(accL, 8);
    accS += __shfl_xor(accS, 8);

    // ---- activations: each 16-lane group computes gate g of both units
    float eL = __expf(-gsc * accL);
    float yL = 1.f / (1.f + eL);
    float actL = (g == 2) ? 2.f * yL - 1.f : yL;
    float eS = __expf(-gsc * accS);
    float yS = 1.f / (1.f + eS);
    float actS = (g == 2) ? 2.f * yS - 1.f : yS;

    float aiL = __shfl(actL, 0), afL = __shfl(actL, 16),
          agL = __shfl(actL, 32), aoL = __shfl(actL, 48);
    float aiS = __shfl(actS, 0), afS = __shfl(actS, 16),
          agS = __shfl(actS, 32), aoS = __shfl(actS, 48);
    if (lane == 0) {
      cstL = afL * cstL + aiL * agL;
      float e2 = __expf(-2.f * cstL);
      float hnL = aoL * (2.f / (1.f + e2) - 1.f);
      ull pkL = ((ull)(unsigned)t << 32) | (ull)__float_as_uint(hnL);
      __hip_atomic_store(&hrec[(size_t)(t & 3) * HDIM + UPW * w + wave], pkL,
                         __ATOMIC_RELAXED, __HIP_MEMORY_SCOPE_AGENT);
      cstS = afS * cstS + aiS * agS;
      float e3 = __expf(-2.f * cstS);
      float hnS = aoS * (2.f / (1.f + e3) - 1.f);
      ull pkS = ((ull)(unsigned)t << 32) | (ull)__float_as_uint(hnS);
      __hip_atomic_store(&hrec[(size_t)(t & 3) * HDIM + UPW * w + 8 + wave],
                         pkS, __ATOMIC_RELAXED, __HIP_MEMORY_SCOPE_AGENT);
    }
    // no end-of-step barrier: publish is self-validating; LDS buffer reuse is
    // two steps away and ordered by the intervening step's __syncthreads.
  }

  // ---- tail step 1: u = tanh(W1 @ h_T + b1), 8 rows per WG ---------------
  {
    // h_T: tag TSTEPS lives in ring parity (TSTEPS & 3) == 0
    const unsigned want = (unsigned)TSTEPS;
    ull v0 = __hip_atomic_load(&hrec[tid], __ATOMIC_RELAXED,
                               __HIP_MEMORY_SCOPE_AGENT);
    ull v1 = __hip_atomic_load(&hrec[tid + NTHR], __ATOMIC_RELAXED,
                               __HIP_MEMORY_SCOPE_AGENT);
    for (;;) {
      bool b0 = (unsigned)(v0 >> 32) == want;
      bool b1 = (unsigned)(v1 >> 32) == want;
      if (b0 && b1) break;
      if (!b0)
        v0 = __hip_atomic_load(&hrec[tid], __ATOMIC_RELAXED,
                               __HIP_MEMORY_SCOPE_AGENT);
      if (!b1)
        v1 = __hip_atomic_load(&hrec[tid + NTHR], __ATOMIC_RELAXED,
                               __HIP_MEMORY_SCOPE_AGENT);
    }
    lds_hf[tid] = __uint_as_float((unsigned)v0);
    lds_hf[tid + NTHR] = __uint_as_float((unsigned)v1);
  }
  __syncthreads();
  {
    int r1 = 8 * w + wave;  // one MLP row per wave, 512 rows over 64 WGs
    const float* w1p = W1 + (size_t)r1 * HDIM + lane * 16;
    float s0 = 0.f, s1 = 0.f;
#pragma unroll
    for (int i = 0; i < 16; i += 2) {
      s0 += w1p[i] * lds_hf[lane * 16 + i];
      s1 += w1p[i + 1] * lds_hf[lane * 16 + i + 1];
    }
    float acc1 = s0 + s1;
#pragma unroll
    for (int m = 1; m < 64; m <<= 1) acc1 += __shfl_xor(acc1, m);
    if (lane == 0) {
      float e2 = __expf(-2.f * (acc1 + b1[r1]));
      float u = 2.f / (1.f + e2) - 1.f;
      ull pk = (1ull << 32) | (ull)__float_as_uint(u);
      __hip_atomic_store(&urec[r1], pk, __ATOMIC_RELAXED,
                         __HIP_MEMORY_SCOPE_AGENT);
    }
  }

  // ---- tail step 2: out = W2 @ u + b2, WG 0 only -------------------------
  if (w == 0) {
    ull uv = __hip_atomic_load(&urec[tid], __ATOMIC_RELAXED,
                               __HIP_MEMORY_SCOPE_AGENT);
    while ((unsigned)(uv >> 32) != 1u)
      uv = __hip_atomic_load(&urec[tid], __ATOMIC_RELAXED,
                             __HIP_MEMORY_SCOPE_AGENT);
    float u = __uint_as_float((unsigned)uv);
    float p0 = W2[tid] * u;
    float p1 = W2[HLDIM + tid] * u;
#pragma unroll
    for (int m = 1; m < 64; m <<= 1) {
      p0 += __shfl_xor(p0, m);
      p1 += __shfl_xor(p1, m);
    }
    if (lane == 0) {
      lds_r0[wave] = p0;
      lds_r1[wave] = p1;
    }
    __syncthreads();
    if (tid == 0) {
      float o0 = b2[0], o1 = b2[1];
#pragma unroll
      for (int k = 0; k < 8; ++k) {
        o0 += lds_r0[k];
        o1 += lds_r1[k];
      }
      out[0] = o0;
      out[1] = o1;
    }
  }
}

extern "C" void kernel_launch(void* const* d_in, const int* in_sizes, int n_in,
                              void* d_out, int out_size, void* d_ws,
                              size_t ws_size, hipStream_t stream) {
  const float* x = (const float*)d_in[0];
  const float* h0 = (const float*)d_in[1];
  const float* c0 = (const float*)d_in[2];
  const float* Wih = (const float*)d_in[3];
  const float* Whh = (const float*)d_in[4];
  const float* bih = (const float*)d_in[5];
  const float* bhh = (const float*)d_in[6];
  const float* W1 = (const float*)d_in[7];
  const float* b1 = (const float*)d_in[8];
  const float* W2 = (const float*)d_in[9];
  const float* b2 = (const float*)d_in[10];
  float* out = (float*)d_out;

  ull* hrec = (ull*)d_ws;                                    // 4*1024*8 = 32 KB
  ull* urec = (ull*)((char*)d_ws + 4 * HDIM * sizeof(ull));  // 4 KB

  k_init<<<1, 1024, 0, stream>>>(h0, hrec, urec);
  k_main<<<NWG, NTHR, 0, stream>>>(x, c0, Wih, Whh, bih, bhh, W1, b1, W2, b2,
                                   out, hrec, urec, 0);
}

// Round 17
// 48662.323 us; speedup vs baseline: 2.0036x; 2.0036x over previous
//
#include <hip/hip_runtime.h>
#include <cstdint>
#include <cstddef>

#define NWG 64
#define NTHR 512
#define TSTEPS 16384
#define HDIM 1024
#define EDIM 13
#define HLDIM 512

typedef unsigned long long ull;

// ---------------------------------------------------------------------------
// FINAL KERNEL — revert to round-13 (best measured: 48.7 ms, ~2.97 us/step).
// Session ledger: 16 rounds, best = this R4-protocol + 90KB-LDS-pad variant.
//   step = detect(~1.5xRTT=1.0us) + publish-visibility(~0.35us)
//        + W-stream/compute serial tail(~1.0-1.3us) + barrier
//        = 2.7-3.0us  ->  44-49 ms at T=16384.  Measured: 48.7 ms.
// Proven dead ends: VGPR W-residency (7 attempts, allocator always spills
// pinned arrays); LDS-resident W (reads can't cross the barrier -> serial);
// pre-poll W prefetch (vmcnt in-order retirement puts W latency into the
// detect path); poll variants (clustered / s_sleep / single-wave /
// dual-chain / wave-specialized all raise MALL contention or serialize);
// 32/128 WGs and 640/1024-thread blocks (rendezvous scales with agents).
// The accidental win kept here: W spilled to private scratch gets its
// reloads pipelined by the compiler into the poll/barrier window.
// ---------------------------------------------------------------------------
__global__ void k_init(const float* __restrict__ h0, ull* __restrict__ hrec,
                       ull* __restrict__ urec) {
  int i = threadIdx.x;
  hrec[i] = (ull)__float_as_uint(h0[i]);  // {h0, tag=0}
  hrec[HDIM + i] = 0ull;
  hrec[2 * HDIM + i] = 0ull;
  hrec[3 * HDIM + i] = 0ull;
  if (i < HLDIM) urec[i] = 0ull;
}

__global__ __launch_bounds__(NTHR)
__attribute__((amdgpu_waves_per_eu(2, 2))) void k_main(
    const float* __restrict__ x, const float* __restrict__ c0,
    const float* __restrict__ Wih, const float* __restrict__ Whh,
    const float* __restrict__ bih, const float* __restrict__ bhh,
    const float* __restrict__ W1, const float* __restrict__ b1,
    const float* __restrict__ W2, const float* __restrict__ b2,
    float* __restrict__ out, ull* hrec, ull* urec, int never) {
  const int w = blockIdx.x;
  const int tid = threadIdx.x;
  const int sub = tid & 7;    // col-chunk index within row (8 x 128 cols)
  const int row = tid >> 3;   // local gate row 0..63
  const int wave = tid >> 6;  // 0..7
  const int lane = tid & 63;
  const int g = row & 3;      // 0=i 1=f 2=g 3=o
  const int lu = row >> 2;    // local unit 0..15
  const int grow = g * HDIM + w * 16 + lu;  // global gate row (gate-major)

  __shared__ float4 lds_h4[2][HDIM / 4];  // double-buffered by step parity
  __shared__ float lds_x[2][16];
  __shared__ float lds_wih[64][17];  // stride 17: conflict-free owner reads
  __shared__ float lds_bsum[64];
  __shared__ float lds_r0[8], lds_r1[8];
  // Occupancy-budget clamp (kept from R13): 1 WG/CU.
  __shared__ float lds_pad[23040];  // 90 KB
  float* lds_hf = (float*)lds_h4;   // [2][1024] flat
  if (never) ((volatile float*)lds_pad)[0] = 1.f;  // keep pad allocated

  // ---- load this thread's W_hh chunk, rotated so the wave's 8 distinct LDS
  // b128 addresses at compute time cover all 32 banks.
  float4 wreg[32];
  const float4* wrow = (const float4*)(Whh + (size_t)grow * HDIM) + sub * 32;
#pragma unroll
  for (int i = 0; i < 32; ++i) wreg[i] = wrow[(i + sub) & 31];
  // Pin: asm claims to rewrite each value -> the compiler spills to private
  // scratch (reloads pipeline into the sync window) instead of
  // rematerializing global loads inside the loop.
#pragma unroll
  for (int i = 0; i < 32; ++i)
    asm volatile("" : "+v"(wreg[i].x), "+v"(wreg[i].y), "+v"(wreg[i].z),
                     "+v"(wreg[i].w));

  if (tid < 64) {
    int g2 = tid & 3, lu2 = tid >> 2;
    int gr2 = g2 * HDIM + w * 16 + lu2;
#pragma unroll
    for (int e = 0; e < EDIM; ++e) lds_wih[tid][e] = Wih[gr2 * EDIM + e];
    lds_bsum[tid] = bih[gr2] + bhh[gr2];
  }
  // cell state: lanes 0 and 32 of each wave own units 2*wave and 2*wave+1
  float cst = c0[w * 16 + 2 * wave + (lane >> 5)];
  __syncthreads();

  const float gsc = (g == 2) ? 2.f : 1.f;  // tanh via 2*sigmoid(2x)-1

  for (int t = 1; t <= TSTEPS; ++t) {
    const int lp = (t - 1) & 1;  // LDS parity (2-deep, barrier-separated)
    // ---- x_t prefetch: issue before the poll so its latency hides there
    float xv = 0.f;
    if (tid < EDIM) xv = x[(size_t)(t - 1) * EDIM + tid];

    // ---- poll this thread's two {h, tag} chunks of h_{t-1}; the poll load
    // IS the data load (one MALL round trip). 4-deep ring: overwrite of a
    // tag-t chunk (by tag t+4) needs three cross-WG dependence chains of
    // separation -> overwrite-before-read unreachable.
    const ull* src = hrec + (size_t)((t - 1) & 3) * HDIM;
    const unsigned want = (unsigned)(t - 1);
    ull v0 = __hip_atomic_load(&src[tid], __ATOMIC_RELAXED,
                               __HIP_MEMORY_SCOPE_AGENT);
    ull v1 = __hip_atomic_load(&src[tid + NTHR], __ATOMIC_RELAXED,
                               __HIP_MEMORY_SCOPE_AGENT);
    for (;;) {
      bool b0 = (unsigned)(v0 >> 32) == want;
      bool b1 = (unsigned)(v1 >> 32) == want;
      if (b0 && b1) break;
      if (!b0)
        v0 = __hip_atomic_load(&src[tid], __ATOMIC_RELAXED,
                               __HIP_MEMORY_SCOPE_AGENT);
      if (!b1)
        v1 = __hip_atomic_load(&src[tid + NTHR], __ATOMIC_RELAXED,
                               __HIP_MEMORY_SCOPE_AGENT);
    }
    lds_hf[lp * HDIM + tid] = __uint_as_float((unsigned)v0);
    lds_hf[lp * HDIM + tid + NTHR] = __uint_as_float((unsigned)v1);
    if (tid < EDIM) lds_x[lp][tid] = xv;
    __syncthreads();

    // ---- gate pre-activation: x-projection folded into the same reduction
    float acc = lds_wih[row][sub] * lds_x[lp][sub];
    if (sub < EDIM - 8) acc += lds_wih[row][sub + 8] * lds_x[lp][sub + 8];
    if (sub == 0) acc += lds_bsum[row];
#pragma unroll
    for (int i = 0; i < 32; ++i) {
      float4 hv = lds_h4[lp][sub * 32 + ((i + sub) & 31)];
      float4 wv = wreg[i];
      acc += wv.x * hv.x;
      acc += wv.y * hv.y;
      acc += wv.z * hv.z;
      acc += wv.w * hv.w;
    }
    acc += __shfl_xor(acc, 1);
    acc += __shfl_xor(acc, 2);
    acc += __shfl_xor(acc, 4);

    // ---- activations computed in parallel on all lanes (one exp chain)
    float e = __expf(-gsc * acc);
    float y = 1.f / (1.f + e);
    float act = (g == 2) ? 2.f * y - 1.f : y;

    int base = lane & 32;
    float ai = __shfl(act, base + 0);
    float af = __shfl(act, base + 8);
    float ag = __shfl(act, base + 16);
    float ao = __shfl(act, base + 24);
    if ((lane & 31) == 0) {
      cst = af * cst + ai * ag;
      float e2 = __expf(-2.f * cst);
      float hn = ao * (2.f / (1.f + e2) - 1.f);
      ull pk = ((ull)(unsigned)t << 32) | (ull)__float_as_uint(hn);
      __hip_atomic_store(&hrec[(size_t)(t & 3) * HDIM + w * 16 + 2 * wave +
                               (lane >> 5)],
                         pk, __ATOMIC_RELAXED, __HIP_MEMORY_SCOPE_AGENT);
    }
    // no end-of-step barrier: publish is self-validating; LDS buffer reuse is
    // two steps away and ordered by the intervening step's __syncthreads.
  }

  // ---- tail step 1: u = tanh(W1 @ h_T + b1), 8 rows per WG --------------
  {
    // h_T: tag TSTEPS lives in ring parity (TSTEPS & 3) == 0
    const unsigned want = (unsigned)TSTEPS;
    ull v0 = __hip_atomic_load(&hrec[tid], __ATOMIC_RELAXED,
                               __HIP_MEMORY_SCOPE_AGENT);
    ull v1 = __hip_atomic_load(&hrec[tid + NTHR], __ATOMIC_RELAXED,
                               __HIP_MEMORY_SCOPE_AGENT);
    for (;;) {
      bool b0 = (unsigned)(v0 >> 32) == want;
      bool b1 = (unsigned)(v1 >> 32) == want;
      if (b0 && b1) break;
      if (!b0)
        v0 = __hip_atomic_load(&hrec[tid], __ATOMIC_RELAXED,
                               __HIP_MEMORY_SCOPE_AGENT);
      if (!b1)
        v1 = __hip_atomic_load(&hrec[tid + NTHR], __ATOMIC_RELAXED,
                               __HIP_MEMORY_SCOPE_AGENT);
    }
    lds_hf[tid] = __uint_as_float((unsigned)v0);
    lds_hf[tid + NTHR] = __uint_as_float((unsigned)v1);
  }
  __syncthreads();
  {
    int r1 = 8 * w + wave;  // one MLP row per wave
    const float* w1p = W1 + (size_t)r1 * HDIM + lane * 16;
    float acc1 = 0.f;
#pragma unroll
    for (int i = 0; i < 16; ++i) acc1 += w1p[i] * lds_hf[lane * 16 + i];
#pragma unroll
    for (int m = 1; m < 64; m <<= 1) acc1 += __shfl_xor(acc1, m);
    if (lane == 0) {
      float e2 = __expf(-2.f * (acc1 + b1[r1]));
      float u = 2.f / (1.f + e2) - 1.f;
      ull pk = (1ull << 32) | (ull)__float_as_uint(u);
      __hip_atomic_store(&urec[r1], pk, __ATOMIC_RELAXED,
                         __HIP_MEMORY_SCOPE_AGENT);
    }
  }

  // ---- tail step 2: out = W2 @ u + b2, WG 0 only -------------------------
  if (w == 0) {
    ull uv = __hip_atomic_load(&urec[tid], __ATOMIC_RELAXED,
                               __HIP_MEMORY_SCOPE_AGENT);
    while ((unsigned)(uv >> 32) != 1u)
      uv = __hip_atomic_load(&urec[tid], __ATOMIC_RELAXED,
                             __HIP_MEMORY_SCOPE_AGENT);
    float u = __uint_as_float((unsigned)uv);
    float p0 = W2[tid] * u;
    float p1 = W2[HLDIM + tid] * u;
#pragma unroll
    for (int m = 1; m < 64; m <<= 1) {
      p0 += __shfl_xor(p0, m);
      p1 += __shfl_xor(p1, m);
    }
    if (lane == 0) {
      lds_r0[wave] = p0;
      lds_r1[wave] = p1;
    }
    __syncthreads();
    if (tid == 0) {
      float o0 = b2[0], o1 = b2[1];
#pragma unroll
      for (int k = 0; k < 8; ++k) {
        o0 += lds_r0[k];
        o1 += lds_r1[k];
      }
      out[0] = o0;
      out[1] = o1;
    }
  }
}

extern "C" void kernel_launch(void* const* d_in, const int* in_sizes, int n_in,
                              void* d_out, int out_size, void* d_ws,
                              size_t ws_size, hipStream_t stream) {
  const float* x = (const float*)d_in[0];
  const float* h0 = (const float*)d_in[1];
  const float* c0 = (const float*)d_in[2];
  const float* Wih = (const float*)d_in[3];
  const float* Whh = (const float*)d_in[4];
  const float* bih = (const float*)d_in[5];
  const float* bhh = (const float*)d_in[6];
  const float* W1 = (const float*)d_in[7];
  const float* b1 = (const float*)d_in[8];
  const float* W2 = (const float*)d_in[9];
  const float* b2 = (const float*)d_in[10];
  float* out = (float*)d_out;

  ull* hrec = (ull*)d_ws;                                    // 4*1024*8 = 32 KB
  ull* urec = (ull*)((char*)d_ws + 4 * HDIM * sizeof(ull));  // 4 KB

  k_init<<<1, 1024, 0, stream>>>(h0, hrec, urec);
  k_main<<<NWG, NTHR, 0, stream>>>(x, c0, Wih, Whh, bih, bhh, W1, b1, W2, b2,
                                   out, hrec, urec, 0);
}